// Round 4
// baseline (116.850 us; speedup 1.0000x reference)
//
#include <hip/hip_runtime.h>
#include <hip/hip_bf16.h>

// MILAttentionPool: B=32, L=2048, D=512, H=256, K=4
// out[b, k*512+d] = sum_l softmax_l(logit[b,l,k]) * x[b*L+l, d]
// logit = (tanh(x@W1+b1)*sigmoid(x@W3+b3)) @ W2   (+b2 cancels in softmax)
//
// R4: occupancy fix. k1 = 256-thr blocks (4 waves 2x2), tile 64x256(concat),
// N-split 2 (partial logits summed later), 42KB LDS, 3 blocks/CU.
// k2/k3/k4 merged into one pooling kernel (per-bag stats computed per block).

typedef short  bf16x8 __attribute__((ext_vector_type(8)));
typedef float  f32x4  __attribute__((ext_vector_type(4)));

#define D_IN    512
#define H_DIM   256
#define L_BAG   2048

__device__ __forceinline__ short f2bf(float f) {
  union { __hip_bfloat16 h; short s; } u;
  u.h = __float2bfloat16(f);
  return u.s;
}

// ---------------- k0: concat-interleaved, N-half-major, chunk-major bf16 weights --------
// wc idx = kt*16384 + nh*8192 + (c*256 + nc_h)*8 + rem
//   k = kt*32 + c*8 + rem; concat col n_c = nh*256 + nc_h; group g=n_c>>5, j=n_c&31:
//   j<16 -> W1[:, g*16+j] else W3[:, g*16+j-16]
__global__ __launch_bounds__(256) void k_prep_w(const float* __restrict__ W1,
                                                const float* __restrict__ W3,
                                                short* __restrict__ wc) {
  int t = blockIdx.x * 256 + threadIdx.x;   // 0..32767
  int n_c = t & 511;
  int kc  = t >> 9;            // k-chunk of 8: 0..63
  int kt = kc >> 2, c = kc & 3;
  int nh = n_c >> 8, nc_h = n_c & 255;
  int g = n_c >> 5, j = n_c & 31;
  const float* src = (j < 16) ? W1 : W3;
  int h = g * 16 + (j & 15);
  bf16x8 v;
  #pragma unroll
  for (int r = 0; r < 8; ++r) v[r] = f2bf(src[(kc * 8 + r) * H_DIM + h]);
  *(bf16x8*)(wc + kt * 16384 + nh * 8192 + (c * 256 + nc_h) * 8) = v;
}

// ---------------- k1: fused gate GEMM (bf16 MFMA) + partial logits ----------------
// 256 thr = 4 waves (2 row x 2 col), wave tile 32x128, block tile 64x256.
// BK=32, 16 K-steps, A+B double-buffered, B via global_load_lds, 1 barrier/step.
__global__ __launch_bounds__(256, 3) void k_gate_logits(
    const float* __restrict__ x,
    const short* __restrict__ wc,
    const float* __restrict__ b1, const float* __restrict__ b3,
    const float* __restrict__ W2,
    float* __restrict__ lp0, float* __restrict__ lp1)
{
  __shared__ __align__(16) short as_[2][2048];   // (c*64 + row)*8   (4 KB each)
  __shared__ __align__(16) short bs_[2][8192];   // (c*256 + col)*8  (16 KB each)
  __shared__ float lpart[2][64][4];              // 2 KB  (total 42 KB)

  const int tid  = threadIdx.x;
  const int lane = tid & 63;
  const int wid  = tid >> 6;
  const int wm   = wid >> 1;      // 0..1 (32-row band)
  const int wn   = wid & 1;       // 0..1 (128-col band)
  const int l15  = lane & 15;
  const int q    = lane >> 4;     // 8-k chunk within 32
  const int nh   = blockIdx.x;    // N-half
  const long row0 = (long)blockIdx.y * 64;

  f32x4 acc[2][8];
  #pragma unroll
  for (int mf = 0; mf < 2; ++mf)
    #pragma unroll
    for (int nf = 0; nf < 8; ++nf) acc[mf][nf] = (f32x4){0.f, 0.f, 0.f, 0.f};

  const int ar = tid & 63;                 // A row (= lane, proven 0-conflict pattern)
  const int ac = tid >> 6;                 // A k-chunk 0..3
  const float* axp = x + (row0 + ar) * D_IN + ac * 8;
  const short* bgp = wc + nh * 8192 + wid * 2048 + lane * 8;

  float4 a0, a1;
#define ALOAD(s) { const float4* p = (const float4*)(axp + (s) * 32); a0 = p[0]; a1 = p[1]; }
#define ASTORE(buf) { bf16x8 v; \
    v[0]=f2bf(a0.x); v[1]=f2bf(a0.y); v[2]=f2bf(a0.z); v[3]=f2bf(a0.w); \
    v[4]=f2bf(a1.x); v[5]=f2bf(a1.y); v[6]=f2bf(a1.z); v[7]=f2bf(a1.w); \
    *(bf16x8*)&as_[buf][(ac * 64 + ar) * 8] = v; }
#define BSTAGE(s, buf) { \
    const short* g_ = bgp + (s) * 16384; \
    _Pragma("unroll") \
    for (int i_ = 0; i_ < 4; ++i_) \
      __builtin_amdgcn_global_load_lds( \
        (const __attribute__((address_space(1))) unsigned int*)(g_ + i_ * 512), \
        (__attribute__((address_space(3))) unsigned int*)&bs_[buf][wid * 2048 + i_ * 512], \
        16, 0, 0); }

  ALOAD(0); BSTAGE(0, 0); ASTORE(0);
  __syncthreads();

  for (int s = 0; s < 16; ++s) {
    const int cb = s & 1;
    if (s < 15) { ALOAD(s + 1); BSTAGE(s + 1, cb ^ 1); }
    bf16x8 af[2], bfr[8];
    #pragma unroll
    for (int mf = 0; mf < 2; ++mf)
      af[mf] = *(const bf16x8*)&as_[cb][(q * 64 + wm * 32 + mf * 16 + l15) * 8];
    #pragma unroll
    for (int nf = 0; nf < 8; ++nf)
      bfr[nf] = *(const bf16x8*)&bs_[cb][(q * 256 + wn * 128 + nf * 16 + l15) * 8];
    #pragma unroll
    for (int mf = 0; mf < 2; ++mf)
      #pragma unroll
      for (int nf = 0; nf < 8; ++nf)
        acc[mf][nf] = __builtin_amdgcn_mfma_f32_16x16x32_bf16(af[mf], bfr[nf], acc[mf][nf], 0, 0, 0);
    if (s < 15) ASTORE(cb ^ 1);
    __syncthreads();
  }

  // epilogue: gate = tanh(h1+b1)*sigmoid(h3+b3); partial logits = gate @ W2
  float b1v[4], b3v[4];
  f32x4 wv[4];
  #pragma unroll
  for (int p = 0; p < 4; ++p) {
    int h = nh * 128 + wn * 64 + p * 16 + l15;
    b1v[p] = b1[h];
    b3v[p] = b3[h];
    wv[p] = *(const f32x4*)&W2[h * 4];
  }
  float pl[2][4][4];
  #pragma unroll
  for (int mf = 0; mf < 2; ++mf)
    #pragma unroll
    for (int j = 0; j < 4; ++j)
      #pragma unroll
      for (int kk = 0; kk < 4; ++kk) pl[mf][j][kk] = 0.f;

  #pragma unroll
  for (int mf = 0; mf < 2; ++mf)
    #pragma unroll
    for (int p = 0; p < 4; ++p)
      #pragma unroll
      for (int j = 0; j < 4; ++j) {
        float h1 = acc[mf][2 * p][j]     + b1v[p];
        float h3 = acc[mf][2 * p + 1][j] + b3v[p];
        float th = 1.f - __fdividef(2.f, __expf(2.f * h1) + 1.f);
        float sg = __fdividef(1.f, 1.f + __expf(-h3));
        float g = th * sg;
        pl[mf][j][0] += g * wv[p][0];
        pl[mf][j][1] += g * wv[p][1];
        pl[mf][j][2] += g * wv[p][2];
        pl[mf][j][3] += g * wv[p][3];
      }

  #pragma unroll
  for (int off = 1; off < 16; off <<= 1)
    #pragma unroll
    for (int mf = 0; mf < 2; ++mf)
      #pragma unroll
      for (int j = 0; j < 4; ++j)
        #pragma unroll
        for (int kk = 0; kk < 4; ++kk)
          pl[mf][j][kk] += __shfl_xor(pl[mf][j][kk], off);

  if (l15 == 0) {
    #pragma unroll
    for (int mf = 0; mf < 2; ++mf)
      #pragma unroll
      for (int j = 0; j < 4; ++j)
        #pragma unroll
        for (int kk = 0; kk < 4; ++kk)
          lpart[wn][wm * 32 + mf * 16 + q * 4 + j][kk] = pl[mf][j][kk];
  }
  __syncthreads();

  {
    int r = tid >> 2, kk = tid & 3;   // 256 threads = 64 rows x 4 heads
    float* lpn = nh ? lp1 : lp0;
    lpn[(row0 + r) * 4 + kk] = lpart[0][r][kk] + lpart[1][r][kk];
  }
}

// ---------------- k3: per-bag softmax stats + weighted column sums -> out ----------------
// grid (8 col-groups of 64, 32 bags), 256 thr. Each block: full-bag stats (redundant
// across the 8 cg blocks, deterministic-identical), then 64-col weighted sum.
__global__ __launch_bounds__(256) void k_pool(const float* __restrict__ x,
                                              const float* __restrict__ lp0,
                                              const float* __restrict__ lp1,
                                              float* __restrict__ out) {
  const int cg  = blockIdx.x;    // 0..7
  const int b   = blockIdx.y;    // 0..31
  const int tid = threadIdx.x;
  const int lane = tid & 63, wid = tid >> 6;

  __shared__ __align__(16) float ep[2048 * 4];   // slot-major: ep[slot*4+k]; slot=(row&127)*16+(row>>7)
  __shared__ __align__(16) float red[16 * 16 * 16]; // [rg][c16][k*4+e]
  __shared__ float stat[4][4];

  // ---- phase A: per-head max over the bag (rows via slot mapping) ----
  const float4* p0 = (const float4*)lp0 + (long)b * L_BAG;
  const float4* p1 = (const float4*)lp1 + (long)b * L_BAG;
  float lg[8][4];
  float m0 = -3e38f, m1 = m0, m2 = m0, m3 = m0;
  #pragma unroll
  for (int i = 0; i < 8; ++i) {
    int s = tid + 256 * i;
    int row = (s >> 4) + (s & 15) * 128;
    float4 u = p0[row], v = p1[row];
    lg[i][0] = u.x + v.x; lg[i][1] = u.y + v.y;
    lg[i][2] = u.z + v.z; lg[i][3] = u.w + v.w;
    m0 = fmaxf(m0, lg[i][0]); m1 = fmaxf(m1, lg[i][1]);
    m2 = fmaxf(m2, lg[i][2]); m3 = fmaxf(m3, lg[i][3]);
  }
  #pragma unroll
  for (int o = 1; o < 64; o <<= 1) {
    m0 = fmaxf(m0, __shfl_xor(m0, o)); m1 = fmaxf(m1, __shfl_xor(m1, o));
    m2 = fmaxf(m2, __shfl_xor(m2, o)); m3 = fmaxf(m3, __shfl_xor(m3, o));
  }
  if (lane == 0) { stat[wid][0] = m0; stat[wid][1] = m1; stat[wid][2] = m2; stat[wid][3] = m3; }
  __syncthreads();
  m0 = fmaxf(fmaxf(stat[0][0], stat[1][0]), fmaxf(stat[2][0], stat[3][0]));
  m1 = fmaxf(fmaxf(stat[0][1], stat[1][1]), fmaxf(stat[2][1], stat[3][1]));
  m2 = fmaxf(fmaxf(stat[0][2], stat[1][2]), fmaxf(stat[2][2], stat[3][2]));
  m3 = fmaxf(fmaxf(stat[0][3], stat[1][3]), fmaxf(stat[2][3], stat[3][3]));
  __syncthreads();

  // ---- phase B: exp + sums; fill ep ----
  float s0 = 0.f, s1 = 0.f, s2 = 0.f, s3 = 0.f;
  #pragma unroll
  for (int i = 0; i < 8; ++i) {
    int s = tid + 256 * i;
    float4 e;
    e.x = __expf(lg[i][0] - m0); e.y = __expf(lg[i][1] - m1);
    e.z = __expf(lg[i][2] - m2); e.w = __expf(lg[i][3] - m3);
    *(float4*)&ep[s * 4] = e;
    s0 += e.x; s1 += e.y; s2 += e.z; s3 += e.w;
  }
  #pragma unroll
  for (int o = 1; o < 64; o <<= 1) {
    s0 += __shfl_xor(s0, o); s1 += __shfl_xor(s1, o);
    s2 += __shfl_xor(s2, o); s3 += __shfl_xor(s3, o);
  }
  if (lane == 0) { stat[wid][0] = s0; stat[wid][1] = s1; stat[wid][2] = s2; stat[wid][3] = s3; }
  __syncthreads();   // covers ep writes + stat
  s0 = stat[0][0] + stat[1][0] + stat[2][0] + stat[3][0];
  s1 = stat[0][1] + stat[1][1] + stat[2][1] + stat[3][1];
  s2 = stat[0][2] + stat[1][2] + stat[2][2] + stat[3][2];
  s3 = stat[0][3] + stat[1][3] + stat[2][3] + stat[3][3];

  // ---- phase C: weighted column sums over 128 rows per thread ----
  const int c16 = lane & 15;            // float4 col within cg
  const int rg  = wid * 4 + (lane >> 4);  // 0..15 row-group of 128
  f32x4 ak0 = {0,0,0,0}, ak1 = {0,0,0,0}, ak2 = {0,0,0,0}, ak3 = {0,0,0,0};
  const float4* xp = (const float4*)(x + ((long)b * L_BAG + rg * 128) * D_IN) + cg * 16 + c16;
  #pragma unroll 4
  for (int rr = 0; rr < 128; ++rr) {
    float4 xv = xp[(long)rr * 128];
    float4 e  = *(const float4*)&ep[(rr * 16 + rg) * 4];
    ak0.x += e.x * xv.x; ak0.y += e.x * xv.y; ak0.z += e.x * xv.z; ak0.w += e.x * xv.w;
    ak1.x += e.y * xv.x; ak1.y += e.y * xv.y; ak1.z += e.y * xv.z; ak1.w += e.y * xv.w;
    ak2.x += e.z * xv.x; ak2.y += e.z * xv.y; ak2.z += e.z * xv.z; ak2.w += e.z * xv.w;
    ak3.x += e.w * xv.x; ak3.y += e.w * xv.y; ak3.z += e.w * xv.z; ak3.w += e.w * xv.w;
  }
  *(f32x4*)&red[((rg * 16 + c16) * 4 + 0) * 4] = ak0;
  *(f32x4*)&red[((rg * 16 + c16) * 4 + 1) * 4] = ak1;
  *(f32x4*)&red[((rg * 16 + c16) * 4 + 2) * 4] = ak2;
  *(f32x4*)&red[((rg * 16 + c16) * 4 + 3) * 4] = ak3;
  __syncthreads();

  // ---- phase D: reduce over 16 row-groups, divide, write ----
  {
    int e  = tid & 3;
    int cf = (tid >> 2) & 15;
    int kf = tid >> 6;
    float v = 0.f;
    #pragma unroll
    for (int r = 0; r < 16; ++r) v += red[((r * 16 + cf) * 4 + kf) * 4 + e];
    float sk = (kf == 0) ? s0 : (kf == 1) ? s1 : (kf == 2) ? s2 : s3;
    out[(long)b * 2048 + kf * 512 + cg * 64 + cf * 4 + e] = v / sk;
  }
}

extern "C" void kernel_launch(void* const* d_in, const int* in_sizes, int n_in,
                              void* d_out, int out_size, void* d_ws, size_t ws_size,
                              hipStream_t stream) {
  const float* x  = (const float*)d_in[0];
  const float* W1 = (const float*)d_in[1];
  const float* b1 = (const float*)d_in[2];
  const float* W3 = (const float*)d_in[3];
  const float* b3 = (const float*)d_in[4];
  const float* W2 = (const float*)d_in[5];
  // d_in[6] = b2: constant over softmax axis -> cancels; d_in[7] = bag_lengths: shapes only
  float* out = (float*)d_out;

  char* ws = (char*)d_ws;                      // 2.6 MB used
  short* wc  = (short*)(ws + 0);               // 512 KB concat bf16 weights
  float* lp0 = (float*)(ws + 524288);          // 1 MB partial logits (N-half 0)
  float* lp1 = (float*)(ws + 1572864);         // 1 MB partial logits (N-half 1)

  hipLaunchKernelGGL(k_prep_w,      dim3(128),      dim3(256), 0, stream, W1, W3, wc);
  hipLaunchKernelGGL(k_gate_logits, dim3(2, 1024),  dim3(256), 0, stream, x, wc, b1, b3, W2, lp0, lp1);
  hipLaunchKernelGGL(k_pool,        dim3(8, 32),    dim3(256), 0, stream, x, lp0, lp1, out);
}

// Round 5
// 107.392 us; speedup vs baseline: 1.0881x; 1.0881x over previous
//
#include <hip/hip_runtime.h>
#include <hip/hip_bf16.h>

// MILAttentionPool: B=32, L=2048, D=512, H=256, K=4
// out[b, k*512+d] = sum_l softmax_l(logit[b,l,k]) * x[b*L+l, d]
// logit = (tanh(x@W1+b1)*sigmoid(x@W3+b3)) @ W2   (+b2 cancels in softmax)
//
// R5: all-register staging (no global_load_lds) so barriers drain lgkmcnt only;
// x prefetched 2 steps ahead (HBM), B 1 step ahead (L2-resident wc), LDS dbuf,
// 16 fully-unrolled K-steps, 1 barrier/step. 42KB LDS, ~150 VGPR, 3 blocks/CU.

typedef short  bf16x8 __attribute__((ext_vector_type(8)));
typedef float  f32x4  __attribute__((ext_vector_type(4)));

#define D_IN    512
#define H_DIM   256
#define L_BAG   2048

__device__ __forceinline__ short f2bf(float f) {
  union { __hip_bfloat16 h; short s; } u;
  u.h = __float2bfloat16(f);
  return u.s;
}

// ---------------- k0: concat-interleaved, N-half-major, chunk-major bf16 weights --------
__global__ __launch_bounds__(256) void k_prep_w(const float* __restrict__ W1,
                                                const float* __restrict__ W3,
                                                short* __restrict__ wc) {
  int t = blockIdx.x * 256 + threadIdx.x;   // 0..32767
  int n_c = t & 511;
  int kc  = t >> 9;            // k-chunk of 8: 0..63
  int kt = kc >> 2, c = kc & 3;
  int nh = n_c >> 8, nc_h = n_c & 255;
  int g = n_c >> 5, j = n_c & 31;
  const float* src = (j < 16) ? W1 : W3;
  int h = g * 16 + (j & 15);
  bf16x8 v;
  #pragma unroll
  for (int r = 0; r < 8; ++r) v[r] = f2bf(src[(kc * 8 + r) * H_DIM + h]);
  *(bf16x8*)(wc + kt * 16384 + nh * 8192 + (c * 256 + nc_h) * 8) = v;
}

// ---------------- k1: fused gate GEMM (bf16 MFMA) + partial logits ----------------
__global__ __launch_bounds__(256, 3) void k_gate_logits(
    const float* __restrict__ x,
    const short* __restrict__ wc,
    const float* __restrict__ b1, const float* __restrict__ b3,
    const float* __restrict__ W2,
    float* __restrict__ lp0, float* __restrict__ lp1)
{
  __shared__ __align__(16) short as_[2][2048];   // A: (c*64 + row)*8    (4 KB each)
  __shared__ __align__(16) short bs_[2][8192];   // B: (c*256 + col)*8   (16 KB each)
  __shared__ float lpart[2][64][4];              // 2 KB  (total 42 KB)

  const int tid  = threadIdx.x;
  const int lane = tid & 63;
  const int wid  = tid >> 6;
  const int wm   = wid >> 1;      // 0..1 (32-row band)
  const int wn   = wid & 1;       // 0..1 (128-col band)
  const int l15  = lane & 15;
  const int q    = lane >> 4;     // 8-k chunk within 32
  const int nh   = blockIdx.x;    // N-half
  const long row0 = (long)blockIdx.y * 64;

  f32x4 acc[2][8];
  #pragma unroll
  for (int mf = 0; mf < 2; ++mf)
    #pragma unroll
    for (int nf = 0; nf < 8; ++nf) acc[mf][nf] = (f32x4){0.f, 0.f, 0.f, 0.f};

  const float* axp = x + (row0 + (tid & 63)) * D_IN + (tid >> 6) * 8;
  const short* bgp = wc + nh * 8192 + tid * 8;
  const int tid8 = tid * 8;

  float4 xp0[2], xp1[2];    // x prefetch, 2 sets (depth 2)
  float4 bp[4];             // B prefetch, 1 set (depth 1, L2)

#define XLOAD(set, s) { const float4* p_ = (const float4*)(axp + (s) * 32); \
    xp0[set] = p_[0]; xp1[set] = p_[1]; }
#define XSTORE(set, buf) { bf16x8 v_; \
    v_[0]=f2bf(xp0[set].x); v_[1]=f2bf(xp0[set].y); v_[2]=f2bf(xp0[set].z); v_[3]=f2bf(xp0[set].w); \
    v_[4]=f2bf(xp1[set].x); v_[5]=f2bf(xp1[set].y); v_[6]=f2bf(xp1[set].z); v_[7]=f2bf(xp1[set].w); \
    *(bf16x8*)&as_[buf][tid8] = v_; }
#define BLOAD(s) { const short* g_ = bgp + (s) * 16384; \
    bp[0] = *(const float4*)(g_);        bp[1] = *(const float4*)(g_ + 2048); \
    bp[2] = *(const float4*)(g_ + 4096); bp[3] = *(const float4*)(g_ + 6144); }
#define BSTORE(buf) { \
    *(float4*)&bs_[buf][tid8]        = bp[0]; *(float4*)&bs_[buf][tid8 + 2048] = bp[1]; \
    *(float4*)&bs_[buf][tid8 + 4096] = bp[2]; *(float4*)&bs_[buf][tid8 + 6144] = bp[3]; }

  // prologue: stage tile 0; prefetch x(1)
  XLOAD(0, 0); BLOAD(0);
  XSTORE(0, 0); BSTORE(0);
  XLOAD(1, 1);
  __syncthreads();

  #pragma unroll
  for (int s = 0; s < 16; ++s) {
    const int cb = s & 1;
    if (s < 15) BLOAD(s + 1);            // L2-resident, ready by step end
    if (s < 14) XLOAD(cb, s + 2);        // HBM, ready by NEXT step end
    bf16x8 af[2], bfr[8];
    #pragma unroll
    for (int mf = 0; mf < 2; ++mf)
      af[mf] = *(const bf16x8*)&as_[cb][(q * 64 + wm * 32 + mf * 16 + l15) * 8];
    #pragma unroll
    for (int nf = 0; nf < 8; ++nf)
      bfr[nf] = *(const bf16x8*)&bs_[cb][(q * 256 + wn * 128 + nf * 16 + l15) * 8];
    #pragma unroll
    for (int mf = 0; mf < 2; ++mf)
      #pragma unroll
      for (int nf = 0; nf < 8; ++nf)
        acc[mf][nf] = __builtin_amdgcn_mfma_f32_16x16x32_bf16(af[mf], bfr[nf], acc[mf][nf], 0, 0, 0);
    if (s < 15) { XSTORE(cb ^ 1, cb ^ 1); BSTORE(cb ^ 1); }
    __syncthreads();
  }

  // epilogue: gate = tanh(h1+b1)*sigmoid(h3+b3); partial logits = gate @ W2
  float b1v[4], b3v[4];
  f32x4 wv[4];
  #pragma unroll
  for (int p = 0; p < 4; ++p) {
    int h = nh * 128 + wn * 64 + p * 16 + l15;
    b1v[p] = b1[h];
    b3v[p] = b3[h];
    wv[p] = *(const f32x4*)&W2[h * 4];
  }
  float pl[2][4][4];
  #pragma unroll
  for (int mf = 0; mf < 2; ++mf)
    #pragma unroll
    for (int j = 0; j < 4; ++j)
      #pragma unroll
      for (int kk = 0; kk < 4; ++kk) pl[mf][j][kk] = 0.f;

  #pragma unroll
  for (int mf = 0; mf < 2; ++mf)
    #pragma unroll
    for (int p = 0; p < 4; ++p)
      #pragma unroll
      for (int j = 0; j < 4; ++j) {
        float h1 = acc[mf][2 * p][j]     + b1v[p];
        float h3 = acc[mf][2 * p + 1][j] + b3v[p];
        float th = 1.f - __fdividef(2.f, __expf(2.f * h1) + 1.f);
        float sg = __fdividef(1.f, 1.f + __expf(-h3));
        float g = th * sg;
        pl[mf][j][0] += g * wv[p][0];
        pl[mf][j][1] += g * wv[p][1];
        pl[mf][j][2] += g * wv[p][2];
        pl[mf][j][3] += g * wv[p][3];
      }

  #pragma unroll
  for (int off = 1; off < 16; off <<= 1)
    #pragma unroll
    for (int mf = 0; mf < 2; ++mf)
      #pragma unroll
      for (int j = 0; j < 4; ++j)
        #pragma unroll
        for (int kk = 0; kk < 4; ++kk)
          pl[mf][j][kk] += __shfl_xor(pl[mf][j][kk], off);

  if (l15 == 0) {
    #pragma unroll
    for (int mf = 0; mf < 2; ++mf)
      #pragma unroll
      for (int j = 0; j < 4; ++j)
        #pragma unroll
        for (int kk = 0; kk < 4; ++kk)
          lpart[wn][wm * 32 + mf * 16 + q * 4 + j][kk] = pl[mf][j][kk];
  }
  __syncthreads();

  {
    int r = tid >> 2, kk = tid & 3;   // 256 threads = 64 rows x 4 heads
    float* lpn = nh ? lp1 : lp0;
    lpn[(row0 + r) * 4 + kk] = lpart[0][r][kk] + lpart[1][r][kk];
  }
}

// ---------------- k3: per-bag softmax stats + weighted column sums -> out ----------------
__global__ __launch_bounds__(256) void k_pool(const float* __restrict__ x,
                                              const float* __restrict__ lp0,
                                              const float* __restrict__ lp1,
                                              float* __restrict__ out) {
  const int cg  = blockIdx.x;    // 0..7
  const int b   = blockIdx.y;    // 0..31
  const int tid = threadIdx.x;
  const int lane = tid & 63, wid = tid >> 6;

  __shared__ __align__(16) float ep[2048 * 4];      // slot-major: slot=(row&127)*16+(row>>7)
  __shared__ __align__(16) float red[16 * 16 * 16]; // [rg][c16][k*4+e]
  __shared__ float stat[4][4];

  // ---- phase A: per-head max over the bag ----
  const float4* p0 = (const float4*)lp0 + (long)b * L_BAG;
  const float4* p1 = (const float4*)lp1 + (long)b * L_BAG;
  float lg[8][4];
  float m0 = -3e38f, m1 = m0, m2 = m0, m3 = m0;
  #pragma unroll
  for (int i = 0; i < 8; ++i) {
    int s = tid + 256 * i;
    int row = (s >> 4) + (s & 15) * 128;
    float4 u = p0[row], v = p1[row];
    lg[i][0] = u.x + v.x; lg[i][1] = u.y + v.y;
    lg[i][2] = u.z + v.z; lg[i][3] = u.w + v.w;
    m0 = fmaxf(m0, lg[i][0]); m1 = fmaxf(m1, lg[i][1]);
    m2 = fmaxf(m2, lg[i][2]); m3 = fmaxf(m3, lg[i][3]);
  }
  #pragma unroll
  for (int o = 1; o < 64; o <<= 1) {
    m0 = fmaxf(m0, __shfl_xor(m0, o)); m1 = fmaxf(m1, __shfl_xor(m1, o));
    m2 = fmaxf(m2, __shfl_xor(m2, o)); m3 = fmaxf(m3, __shfl_xor(m3, o));
  }
  if (lane == 0) { stat[wid][0] = m0; stat[wid][1] = m1; stat[wid][2] = m2; stat[wid][3] = m3; }
  __syncthreads();
  m0 = fmaxf(fmaxf(stat[0][0], stat[1][0]), fmaxf(stat[2][0], stat[3][0]));
  m1 = fmaxf(fmaxf(stat[0][1], stat[1][1]), fmaxf(stat[2][1], stat[3][1]));
  m2 = fmaxf(fmaxf(stat[0][2], stat[1][2]), fmaxf(stat[2][2], stat[3][2]));
  m3 = fmaxf(fmaxf(stat[0][3], stat[1][3]), fmaxf(stat[2][3], stat[3][3]));
  __syncthreads();

  // ---- phase B: exp + sums; fill ep ----
  float s0 = 0.f, s1 = 0.f, s2 = 0.f, s3 = 0.f;
  #pragma unroll
  for (int i = 0; i < 8; ++i) {
    int s = tid + 256 * i;
    float4 e;
    e.x = __expf(lg[i][0] - m0); e.y = __expf(lg[i][1] - m1);
    e.z = __expf(lg[i][2] - m2); e.w = __expf(lg[i][3] - m3);
    *(float4*)&ep[s * 4] = e;
    s0 += e.x; s1 += e.y; s2 += e.z; s3 += e.w;
  }
  #pragma unroll
  for (int o = 1; o < 64; o <<= 1) {
    s0 += __shfl_xor(s0, o); s1 += __shfl_xor(s1, o);
    s2 += __shfl_xor(s2, o); s3 += __shfl_xor(s3, o);
  }
  if (lane == 0) { stat[wid][0] = s0; stat[wid][1] = s1; stat[wid][2] = s2; stat[wid][3] = s3; }
  __syncthreads();
  s0 = stat[0][0] + stat[1][0] + stat[2][0] + stat[3][0];
  s1 = stat[0][1] + stat[1][1] + stat[2][1] + stat[3][1];
  s2 = stat[0][2] + stat[1][2] + stat[2][2] + stat[3][2];
  s3 = stat[0][3] + stat[1][3] + stat[2][3] + stat[3][3];

  // ---- phase C: weighted column sums over 128 rows per thread ----
  const int c16 = lane & 15;
  const int rg  = wid * 4 + (lane >> 4);
  f32x4 ak0 = {0,0,0,0}, ak1 = {0,0,0,0}, ak2 = {0,0,0,0}, ak3 = {0,0,0,0};
  const float4* xp = (const float4*)(x + ((long)b * L_BAG + rg * 128) * D_IN) + cg * 16 + c16;
  #pragma unroll 4
  for (int rr = 0; rr < 128; ++rr) {
    float4 xv = xp[(long)rr * 128];
    float4 e  = *(const float4*)&ep[(rr * 16 + rg) * 4];
    ak0.x += e.x * xv.x; ak0.y += e.x * xv.y; ak0.z += e.x * xv.z; ak0.w += e.x * xv.w;
    ak1.x += e.y * xv.x; ak1.y += e.y * xv.y; ak1.z += e.y * xv.z; ak1.w += e.y * xv.w;
    ak2.x += e.z * xv.x; ak2.y += e.z * xv.y; ak2.z += e.z * xv.z; ak2.w += e.z * xv.w;
    ak3.x += e.w * xv.x; ak3.y += e.w * xv.y; ak3.z += e.w * xv.z; ak3.w += e.w * xv.w;
  }
  *(f32x4*)&red[((rg * 16 + c16) * 4 + 0) * 4] = ak0;
  *(f32x4*)&red[((rg * 16 + c16) * 4 + 1) * 4] = ak1;
  *(f32x4*)&red[((rg * 16 + c16) * 4 + 2) * 4] = ak2;
  *(f32x4*)&red[((rg * 16 + c16) * 4 + 3) * 4] = ak3;
  __syncthreads();

  // ---- phase D: reduce over 16 row-groups, divide, write ----
  {
    int e  = tid & 3;
    int cf = (tid >> 2) & 15;
    int kf = tid >> 6;
    float v = 0.f;
    #pragma unroll
    for (int r = 0; r < 16; ++r) v += red[((r * 16 + cf) * 4 + kf) * 4 + e];
    float sk = (kf == 0) ? s0 : (kf == 1) ? s1 : (kf == 2) ? s2 : s3;
    out[(long)b * 2048 + kf * 512 + cg * 64 + cf * 4 + e] = v / sk;
  }
}

extern "C" void kernel_launch(void* const* d_in, const int* in_sizes, int n_in,
                              void* d_out, int out_size, void* d_ws, size_t ws_size,
                              hipStream_t stream) {
  const float* x  = (const float*)d_in[0];
  const float* W1 = (const float*)d_in[1];
  const float* b1 = (const float*)d_in[2];
  const float* W3 = (const float*)d_in[3];
  const float* b3 = (const float*)d_in[4];
  const float* W2 = (const float*)d_in[5];
  // d_in[6] = b2: cancels in softmax; d_in[7] = bag_lengths: shapes only
  float* out = (float*)d_out;

  char* ws = (char*)d_ws;                      // 2.6 MB used
  short* wc  = (short*)(ws + 0);               // 512 KB concat bf16 weights
  float* lp0 = (float*)(ws + 524288);          // 1 MB partial logits (N-half 0)
  float* lp1 = (float*)(ws + 1572864);         // 1 MB partial logits (N-half 1)

  hipLaunchKernelGGL(k_prep_w,      dim3(128),      dim3(256), 0, stream, W1, W3, wc);
  hipLaunchKernelGGL(k_gate_logits, dim3(2, 1024),  dim3(256), 0, stream, x, wc, b1, b3, W2, lp0, lp1);
  hipLaunchKernelGGL(k_pool,        dim3(8, 32),    dim3(256), 0, stream, x, lp0, lp1, out);
}